// Round 7
// baseline (66886.829 us; speedup 1.0000x reference)
//
#include <hip/hip_runtime.h>
#include <hip/hip_bf16.h>

#define BATCH 8
#define SEQ   2048
#define DIM   1024
#define NLAYER 2

typedef float  f32x4 __attribute__((ext_vector_type(4)));
typedef float  f32x2 __attribute__((ext_vector_type(2)));
typedef short  s16x8 __attribute__((ext_vector_type(8)));
typedef unsigned short u16x4 __attribute__((ext_vector_type(4)));

// =====================================================================
// bf16x3 split-precision MFMA GEMM: x = hi + lo (both bf16);
// x*y ~= hi*hi' + hi*lo' + lo*hi'  (fp32-class accuracy, ~3x fp32 speed)
// Used for ALL GEMMs now: the tanh recurrence is contractive
// (||Whh|| ~ 0.6 < 1), so ~1e-5 noise on scan inputs decays, and the
// absmax has 50% headroom to threshold.
// =====================================================================
__device__ __forceinline__ unsigned short bf16_rne(float x) {
  const unsigned u = __float_as_uint(x);
  return (unsigned short)((u + 0x7FFFu + ((u >> 16) & 1u)) >> 16);
}
__device__ __forceinline__ void split_bf16(float x, unsigned short& hi, unsigned short& lo) {
  hi = bf16_rne(x);
  const float hf = __uint_as_float((unsigned)hi << 16);
  lo = bf16_rne(x - hf);
}

template<int TRANSB>
__global__ __launch_bounds__(256)
void gemm_bf16x3(const float* __restrict__ A, const float* __restrict__ B,
                 const float* __restrict__ bias, float* __restrict__ C,
                 int M, int N, int K, float alpha,
                 long long strideA, long long strideB, long long strideC)
{
  constexpr int LK = 40;
  __shared__ unsigned short Ah[128 * LK], Al[128 * LK];
  __shared__ unsigned short Bh[128 * LK], Bl[128 * LK];

  const int z = blockIdx.z;
  A += (size_t)z * strideA;
  B += (size_t)z * strideB;
  C += (size_t)z * strideC;

  const int tid  = threadIdx.x;
  const int row0 = blockIdx.x * 128;
  const int col0 = blockIdx.y * 128;
  const int w    = tid >> 6;
  const int lane = tid & 63;
  const int m0   = (w >> 1) * 64;
  const int n0   = (w & 1) * 64;
  const int half = lane >> 4;
  const int mr   = lane & 15;

  f32x4 acc[4][4];
#pragma unroll
  for (int i = 0; i < 4; ++i)
#pragma unroll
    for (int j = 0; j < 4; ++j) acc[i][j] = (f32x4){0.f, 0.f, 0.f, 0.f};

  for (int k0 = 0; k0 < K; k0 += 32) {
    __syncthreads();
    {
      const int r = tid >> 3, c4 = tid & 7;
#pragma unroll
      for (int rep = 0; rep < 4; ++rep) {
        const int row = r + rep * 32;
        const float4 v = *(const float4*)&A[(size_t)(row0 + row) * K + k0 + c4 * 4];
        unsigned short h0,h1,h2,h3,l0,l1,l2,l3;
        split_bf16(v.x, h0, l0); split_bf16(v.y, h1, l1);
        split_bf16(v.z, h2, l2); split_bf16(v.w, h3, l3);
        *(u16x4*)&Ah[row * LK + c4 * 4] = (u16x4){h0, h1, h2, h3};
        *(u16x4*)&Al[row * LK + c4 * 4] = (u16x4){l0, l1, l2, l3};
      }
    }
    if (TRANSB) {
      const int r = tid >> 3, c4 = tid & 7;
#pragma unroll
      for (int rep = 0; rep < 4; ++rep) {
        const int row = r + rep * 32;
        const float4 v = *(const float4*)&B[(size_t)(col0 + row) * K + k0 + c4 * 4];
        unsigned short h0,h1,h2,h3,l0,l1,l2,l3;
        split_bf16(v.x, h0, l0); split_bf16(v.y, h1, l1);
        split_bf16(v.z, h2, l2); split_bf16(v.w, h3, l3);
        *(u16x4*)&Bh[row * LK + c4 * 4] = (u16x4){h0, h1, h2, h3};
        *(u16x4*)&Bl[row * LK + c4 * 4] = (u16x4){l0, l1, l2, l3};
      }
    } else {
      const int kk8 = tid >> 5, n4 = tid & 31;
#pragma unroll
      for (int rep = 0; rep < 4; ++rep) {
        const int kk = kk8 + rep * 8;
        const float4 v = *(const float4*)&B[(size_t)(k0 + kk) * N + col0 + n4 * 4];
        unsigned short h, l;
        split_bf16(v.x, h, l); Bh[(n4*4+0)*LK + kk] = h; Bl[(n4*4+0)*LK + kk] = l;
        split_bf16(v.y, h, l); Bh[(n4*4+1)*LK + kk] = h; Bl[(n4*4+1)*LK + kk] = l;
        split_bf16(v.z, h, l); Bh[(n4*4+2)*LK + kk] = h; Bl[(n4*4+2)*LK + kk] = l;
        split_bf16(v.w, h, l); Bh[(n4*4+3)*LK + kk] = h; Bl[(n4*4+3)*LK + kk] = l;
      }
    }
    __syncthreads();

    s16x8 ah[4], al[4], bh[4], bl[4];
#pragma unroll
    for (int i = 0; i < 4; ++i) {
      ah[i] = *(const s16x8*)&Ah[(m0 + i*16 + mr) * LK + half * 8];
      al[i] = *(const s16x8*)&Al[(m0 + i*16 + mr) * LK + half * 8];
      bh[i] = *(const s16x8*)&Bh[(n0 + i*16 + mr) * LK + half * 8];
      bl[i] = *(const s16x8*)&Bl[(n0 + i*16 + mr) * LK + half * 8];
    }
#pragma unroll
    for (int i = 0; i < 4; ++i)
#pragma unroll
      for (int j = 0; j < 4; ++j) {
        acc[i][j] = __builtin_amdgcn_mfma_f32_16x16x32_bf16(ah[i], bh[j], acc[i][j], 0, 0, 0);
        acc[i][j] = __builtin_amdgcn_mfma_f32_16x16x32_bf16(ah[i], bl[j], acc[i][j], 0, 0, 0);
        acc[i][j] = __builtin_amdgcn_mfma_f32_16x16x32_bf16(al[i], bh[j], acc[i][j], 0, 0, 0);
      }
  }

#pragma unroll
  for (int j = 0; j < 4; ++j) {
    const int col = col0 + n0 + j * 16 + mr;
    const float bb = bias ? bias[col] : 0.f;
#pragma unroll
    for (int i = 0; i < 4; ++i) {
#pragma unroll
      for (int q = 0; q < 4; ++q) {
        const int row = row0 + m0 + i * 16 + half * 4 + q;
        C[(size_t)row * N + col] = fmaf(alpha, acc[i][j][q], bb);
      }
    }
  }
}

// =====================================================================
// tanh without an OCML call (abs err ~1e-7)
// =====================================================================
__device__ __forceinline__ float fast_tanh(float x) {
  const float a = fabsf(x);
  const float e = __expf(2.0f * a);
  const float t = 1.0f - 2.0f / (e + 1.0f);
  return copysignf(t, x);
}

// =====================================================================
// RNN scan v5 — attack the per-step serial chain (rounds 3-6 proved
// weight placement is NOT the bottleneck: 5.2-5.8ms for L2/scratch/LDS).
//  - k-split: wave w owns k in [w*128, w*128+128) for ALL 32 dims.
//  - Each wave SELF-POLLS only its 8B/lane slice of h_{t-1} (one
//    dwordx2 spin; no wave0 broadcast, no broadcast barrier).
//  - 32 accumulators/lane, 5-round multi-value butterfly (lane l ends
//    holding dim bitrev5(l&31)); partials to double-buffered LDS;
//    ONE __syncthreads per step; wave0 lanes<32 do the 8-way final
//    sum + bias + tanh and ONE coalesced 128B line store (sc0 sc1)
//    per WG per step (fixes the partial-line WRITE_SIZE 2x).
//  - Weights staged to LDS once, then read to wr[32] regs PRE-LOOP
//    (loop-invariant). If the allocator rematerializes from LDS per
//    step, that fallback is exactly the round-6 design — no worse.
// Data-as-flag: h buffer pre-poisoned 0xFFFFFFFF (NaN; tanh never
// produces it); stores write-through sc0 sc1; polls bypass L1/L2.
// 256 WGs (batch, dim-block) = 1/CU -> co-resident.
// =====================================================================
__global__ __launch_bounds__(512, 1)
void rnn_scan(const float* __restrict__ Pre, float* __restrict__ Hout,
              const float* __restrict__ Whh, const float* __restrict__ bhh)
{
  __shared__ float wS[32][DIM];      // 128 KB
  __shared__ float pS[2][8][33];     // per-wave partials, padded
  const int b    = blockIdx.x & 7;
  const int p    = blockIdx.x >> 3;      // 0..31
  const int wv   = threadIdx.x >> 6;     // 0..7
  const int lane = threadIdx.x & 63;
  const int l5   = lane & 31;
  const int drev = ((l5 & 1) << 4) | ((l5 & 2) << 2) | (l5 & 4)
                 | ((l5 & 8) >> 2) | ((l5 & 16) >> 4);   // bitrev5

  const float* PreB = Pre  + (size_t)b * SEQ * DIM;
  float*       HB   = Hout + (size_t)b * SEQ * DIM;

  // stage this WG's 32 weight rows into LDS (coalesced float4)
  for (int i = threadIdx.x; i < 32 * (DIM / 4); i += 512) {
    const int row = i >> 8, c4 = i & 255;
    *(f32x4*)&wS[row][c4 * 4] =
        *(const f32x4*)&Whh[(size_t)(p * 32 + row) * DIM + c4 * 4];
  }
  __syncthreads();

  const int  k0     = wv * 128 + lane * 2;       // this lane's k-pair
  const bool w0lane = (wv == 0) && (lane < 32);
  const float biasv = w0lane ? bhh[p * 32 + lane] : 0.f;

  // loop-invariant weight fragments (hopefully register-resident;
  // fallback = per-step LDS reads, which is fine)
  f32x2 wr[32];
#pragma unroll
  for (int d = 0; d < 32; ++d) wr[d] = *(const f32x2*)&wS[d][k0];

  for (int t = 0; t < SEQ; ++t) {
    float pre = 0.f;
    if (w0lane) pre = PreB[(size_t)t * DIM + p * 32 + lane];

    float acc[32];
    if (t > 0) {
      const float* hp = HB + (size_t)(t - 1) * DIM + k0;
      f32x2 h2;
      while (true) {
        asm volatile(
          "global_load_dwordx2 %0, %1, off sc0 sc1\n\t"
          "s_waitcnt vmcnt(0)"
          : "=&v"(h2) : "v"(hp));
        const bool good = (__float_as_uint(h2.x) != 0xFFFFFFFFu) &&
                          (__float_as_uint(h2.y) != 0xFFFFFFFFu);
        if (__all(good)) break;
      }
#pragma unroll
      for (int d = 0; d < 32; ++d)
        acc[d] = fmaf(wr[d].x, h2.x, wr[d].y * h2.y);
    } else {
#pragma unroll
      for (int d = 0; d < 32; ++d) acc[d] = 0.f;
    }

    // fold 32 accs across lanes: masks 1,2,4,8,16 halve the count,
    // then mask 32 finishes. Lane l ends holding dim bitrev5(l&31).
#pragma unroll
    for (int m = 0; m < 5; ++m) {
      const int mask = 1 << m;
      const int nv   = 16 >> m;
      const bool up  = (lane & mask) != 0;
#pragma unroll
      for (int r = 0; r < nv; ++r) {
        const float lo = up ? acc[r + nv] : acc[r];
        const float hi = up ? acc[r] : acc[r + nv];
        acc[r] = lo + __shfl_xor(hi, mask);
      }
    }
    acc[0] += __shfl_xor(acc[0], 32);

    if (lane < 32) pS[t & 1][wv][drev] = acc[0];
    __syncthreads();

    if (w0lane) {
      float s = pre + biasv;
#pragma unroll
      for (int j = 0; j < 8; ++j) s += pS[t & 1][j][lane];
      const float v = fast_tanh(s);
      float* dst = HB + (size_t)t * DIM + p * 32 + lane;
      asm volatile("global_store_dword %0, %1, off sc0 sc1"
                   :: "v"(dst), "v"(v));
    }
  }
}

// =====================================================================
// Masked softmax, in place, one row per block
// =====================================================================
__global__ __launch_bounds__(256)
void softmax_mask(float* __restrict__ S, const unsigned char* __restrict__ mask)
{
  const size_t row = (size_t)blockIdx.y * gridDim.x + blockIdx.x;
  float* p = S + row * SEQ;
  const unsigned char* mrow = mask + row * SEQ;
  __shared__ float buf[SEQ];
  __shared__ float red[4];
  const int tid = threadIdx.x, lane = tid & 63, wv = tid >> 6;

  float mx = -1e30f;
  for (int i = tid; i < SEQ; i += 256) {
    const float v = mrow[i] ? -1e9f : p[i];
    buf[i] = v;
    mx = fmaxf(mx, v);
  }
#pragma unroll
  for (int off = 1; off < 64; off <<= 1) mx = fmaxf(mx, __shfl_xor(mx, off));
  if (lane == 0) red[wv] = mx;
  __syncthreads();
  mx = fmaxf(fmaxf(red[0], red[1]), fmaxf(red[2], red[3]));

  float s = 0.f;
  for (int i = tid; i < SEQ; i += 256) {
    const float e = __expf(buf[i] - mx);
    buf[i] = e;
    s += e;
  }
#pragma unroll
  for (int off = 1; off < 64; off <<= 1) s += __shfl_xor(s, off);
  __syncthreads();
  if (lane == 0) red[wv] = s;
  __syncthreads();
  s = red[0] + red[1] + red[2] + red[3];
  const float inv = 1.f / s;
  for (int i = tid; i < SEQ; i += 256) p[i] = buf[i] * inv;
}

// =====================================================================
extern "C" void kernel_launch(void* const* d_in, const int* in_sizes, int n_in,
                              void* d_out, int out_size, void* d_ws, size_t ws_size,
                              hipStream_t stream)
{
  (void)in_sizes; (void)n_in; (void)out_size;
  const unsigned char* mask = (const unsigned char*)d_in[0];
  const float* reps = (const float*)d_in[1];
  const float* Wih  = (const float*)d_in[2];
  const float* Whh  = (const float*)d_in[3];
  const float* bih  = (const float*)d_in[4];
  const float* bhh  = (const float*)d_in[5];
  const float* Wq   = (const float*)d_in[6];
  const float* bq   = (const float*)d_in[7];
  const float* Wk   = (const float*)d_in[8];
  const float* bk   = (const float*)d_in[9];
  const float* Wv   = (const float*)d_in[10];
  const float* bv   = (const float*)d_in[11];
  const float* Wo   = (const float*)d_in[12];
  const float* bo   = (const float*)d_in[13];
  float* out = (float*)d_out;

  char* ws = (char*)d_ws;
  float* Hb = (float*)(ws);
  float* Qb = (float*)(ws + ((size_t)64  << 20));
  float* Kb = (float*)(ws + ((size_t)128 << 20));
  float* Vb = (float*)(ws + ((size_t)192 << 20));
  float* Sb = (float*)(ws + ((size_t)256 << 20));
  const size_t needFull = ((size_t)256 << 20) + (size_t)BATCH * SEQ * SEQ * 4;
  const bool fullS = ws_size >= needFull;
  const size_t hBytes = (size_t)BATCH * SEQ * DIM * 4;

  const int M1 = BATCH * SEQ;
  const float scale = 0.03125f;
  const dim3 blk(256);
  const long long sSD = (long long)SEQ * DIM;
  const long long sSS = (long long)SEQ * SEQ;

  const float* X = reps;
  for (int l = 0; l < NLAYER; ++l) {
    const size_t wof = (size_t)l * DIM * DIM;
    const size_t bof = (size_t)l * DIM;
    float* Y = (l == NLAYER - 1) ? out : Qb;

    hipMemsetAsync(Hb, 0xFF, hBytes, stream);
    // Pre = X @ Wih^T + bih (bf16x3 now: recurrence is contractive)
    gemm_bf16x3<1><<<dim3(M1/128, DIM/128, 1), blk, 0, stream>>>(
        X, Wih + wof, bih + bof, Kb, M1, DIM, DIM, 1.f, 0, 0, 0);
    rnn_scan<<<dim3(256), dim3(512), 0, stream>>>(Kb, Hb, Whh + wof, bhh + bof);

    gemm_bf16x3<1><<<dim3(M1/128, DIM/128, 1), blk, 0, stream>>>(
        Hb, Wq + wof, bq + bof, Qb, M1, DIM, DIM, 1.f, 0, 0, 0);
    gemm_bf16x3<1><<<dim3(M1/128, DIM/128, 1), blk, 0, stream>>>(
        Hb, Wk + wof, bk + bof, Kb, M1, DIM, DIM, 1.f, 0, 0, 0);
    gemm_bf16x3<1><<<dim3(M1/128, DIM/128, 1), blk, 0, stream>>>(
        Hb, Wv + wof, bv + bof, Vb, M1, DIM, DIM, 1.f, 0, 0, 0);

    if (fullS) {
      gemm_bf16x3<1><<<dim3(SEQ/128, SEQ/128, BATCH), blk, 0, stream>>>(
          Qb, Kb, nullptr, Sb, SEQ, SEQ, DIM, scale, sSD, sSD, sSS);
      softmax_mask<<<dim3(SEQ, BATCH), blk, 0, stream>>>(Sb, mask);
      gemm_bf16x3<0><<<dim3(SEQ/128, DIM/128, BATCH), blk, 0, stream>>>(
          Sb, Vb, nullptr, Hb, SEQ, DIM, SEQ, 1.f, sSS, sSD, sSD);
    } else {
      for (int bb = 0; bb < BATCH; ++bb) {
        gemm_bf16x3<1><<<dim3(SEQ/128, SEQ/128, 1), blk, 0, stream>>>(
            Qb + (size_t)bb * sSD, Kb + (size_t)bb * sSD, nullptr, Sb,
            SEQ, SEQ, DIM, scale, 0, 0, 0);
        softmax_mask<<<dim3(SEQ, 1), blk, 0, stream>>>(Sb, mask + (size_t)bb * sSS);
        gemm_bf16x3<0><<<dim3(SEQ/128, DIM/128, 1), blk, 0, stream>>>(
            Sb, Vb + (size_t)bb * sSD, nullptr, Hb + (size_t)bb * sSD,
            SEQ, DIM, SEQ, 1.f, 0, 0, 0);
      }
    }
    gemm_bf16x3<1><<<dim3(M1/128, DIM/128, 1), blk, 0, stream>>>(
        Hb, Wo + wof, bo + bof, Y, M1, DIM, DIM, 1.f, 0, 0, 0);
    X = Y;
  }
}

// Round 8
// 13053.253 us; speedup vs baseline: 5.1242x; 5.1242x over previous
//
#include <hip/hip_runtime.h>
#include <hip/hip_bf16.h>

#define BATCH 8
#define SEQ   2048
#define DIM   1024
#define NLAYER 2

typedef float  f32x4 __attribute__((ext_vector_type(4)));
typedef short  s16x8 __attribute__((ext_vector_type(8)));
typedef unsigned short u16x4 __attribute__((ext_vector_type(4)));

// =====================================================================
// bf16x3 split-precision MFMA GEMM (all GEMMs; recurrence is
// contractive so ~1e-5 noise on scan inputs decays — proven r7:
// absmax unchanged at 0.0009765625 with all GEMMs on this path)
// =====================================================================
__device__ __forceinline__ unsigned short bf16_rne(float x) {
  const unsigned u = __float_as_uint(x);
  return (unsigned short)((u + 0x7FFFu + ((u >> 16) & 1u)) >> 16);
}
__device__ __forceinline__ void split_bf16(float x, unsigned short& hi, unsigned short& lo) {
  hi = bf16_rne(x);
  const float hf = __uint_as_float((unsigned)hi << 16);
  lo = bf16_rne(x - hf);
}

template<int TRANSB>
__global__ __launch_bounds__(256)
void gemm_bf16x3(const float* __restrict__ A, const float* __restrict__ B,
                 const float* __restrict__ bias, float* __restrict__ C,
                 int M, int N, int K, float alpha,
                 long long strideA, long long strideB, long long strideC)
{
  constexpr int LK = 40;
  __shared__ unsigned short Ah[128 * LK], Al[128 * LK];
  __shared__ unsigned short Bh[128 * LK], Bl[128 * LK];

  const int z = blockIdx.z;
  A += (size_t)z * strideA;
  B += (size_t)z * strideB;
  C += (size_t)z * strideC;

  const int tid  = threadIdx.x;
  const int row0 = blockIdx.x * 128;
  const int col0 = blockIdx.y * 128;
  const int w    = tid >> 6;
  const int lane = tid & 63;
  const int m0   = (w >> 1) * 64;
  const int n0   = (w & 1) * 64;
  const int half = lane >> 4;
  const int mr   = lane & 15;

  f32x4 acc[4][4];
#pragma unroll
  for (int i = 0; i < 4; ++i)
#pragma unroll
    for (int j = 0; j < 4; ++j) acc[i][j] = (f32x4){0.f, 0.f, 0.f, 0.f};

  for (int k0 = 0; k0 < K; k0 += 32) {
    __syncthreads();
    {
      const int r = tid >> 3, c4 = tid & 7;
#pragma unroll
      for (int rep = 0; rep < 4; ++rep) {
        const int row = r + rep * 32;
        const float4 v = *(const float4*)&A[(size_t)(row0 + row) * K + k0 + c4 * 4];
        unsigned short h0,h1,h2,h3,l0,l1,l2,l3;
        split_bf16(v.x, h0, l0); split_bf16(v.y, h1, l1);
        split_bf16(v.z, h2, l2); split_bf16(v.w, h3, l3);
        *(u16x4*)&Ah[row * LK + c4 * 4] = (u16x4){h0, h1, h2, h3};
        *(u16x4*)&Al[row * LK + c4 * 4] = (u16x4){l0, l1, l2, l3};
      }
    }
    if (TRANSB) {
      const int r = tid >> 3, c4 = tid & 7;
#pragma unroll
      for (int rep = 0; rep < 4; ++rep) {
        const int row = r + rep * 32;
        const float4 v = *(const float4*)&B[(size_t)(col0 + row) * K + k0 + c4 * 4];
        unsigned short h0,h1,h2,h3,l0,l1,l2,l3;
        split_bf16(v.x, h0, l0); split_bf16(v.y, h1, l1);
        split_bf16(v.z, h2, l2); split_bf16(v.w, h3, l3);
        *(u16x4*)&Bh[row * LK + c4 * 4] = (u16x4){h0, h1, h2, h3};
        *(u16x4*)&Bl[row * LK + c4 * 4] = (u16x4){l0, l1, l2, l3};
      }
    } else {
      const int kk8 = tid >> 5, n4 = tid & 31;
#pragma unroll
      for (int rep = 0; rep < 4; ++rep) {
        const int kk = kk8 + rep * 8;
        const float4 v = *(const float4*)&B[(size_t)(k0 + kk) * N + col0 + n4 * 4];
        unsigned short h, l;
        split_bf16(v.x, h, l); Bh[(n4*4+0)*LK + kk] = h; Bl[(n4*4+0)*LK + kk] = l;
        split_bf16(v.y, h, l); Bh[(n4*4+1)*LK + kk] = h; Bl[(n4*4+1)*LK + kk] = l;
        split_bf16(v.z, h, l); Bh[(n4*4+2)*LK + kk] = h; Bl[(n4*4+2)*LK + kk] = l;
        split_bf16(v.w, h, l); Bh[(n4*4+3)*LK + kk] = h; Bl[(n4*4+3)*LK + kk] = l;
      }
    }
    __syncthreads();

    s16x8 ah[4], al[4], bh[4], bl[4];
#pragma unroll
    for (int i = 0; i < 4; ++i) {
      ah[i] = *(const s16x8*)&Ah[(m0 + i*16 + mr) * LK + half * 8];
      al[i] = *(const s16x8*)&Al[(m0 + i*16 + mr) * LK + half * 8];
      bh[i] = *(const s16x8*)&Bh[(n0 + i*16 + mr) * LK + half * 8];
      bl[i] = *(const s16x8*)&Bl[(n0 + i*16 + mr) * LK + half * 8];
    }
#pragma unroll
    for (int i = 0; i < 4; ++i)
#pragma unroll
      for (int j = 0; j < 4; ++j) {
        acc[i][j] = __builtin_amdgcn_mfma_f32_16x16x32_bf16(ah[i], bh[j], acc[i][j], 0, 0, 0);
        acc[i][j] = __builtin_amdgcn_mfma_f32_16x16x32_bf16(ah[i], bl[j], acc[i][j], 0, 0, 0);
        acc[i][j] = __builtin_amdgcn_mfma_f32_16x16x32_bf16(al[i], bh[j], acc[i][j], 0, 0, 0);
      }
  }

#pragma unroll
  for (int j = 0; j < 4; ++j) {
    const int col = col0 + n0 + j * 16 + mr;
    const float bb = bias ? bias[col] : 0.f;
#pragma unroll
    for (int i = 0; i < 4; ++i) {
#pragma unroll
      for (int q = 0; q < 4; ++q) {
        const int row = row0 + m0 + i * 16 + half * 4 + q;
        C[(size_t)row * N + col] = fmaf(alpha, acc[i][j][q], bb);
      }
    }
  }
}

// =====================================================================
// tanh without an OCML call (abs err ~1e-7)
// =====================================================================
__device__ __forceinline__ float fast_tanh(float x) {
  const float a = fabsf(x);
  const float e = __expf(2.0f * a);
  const float t = 1.0f - 2.0f / (e + 1.0f);
  return copysignf(t, x);
}

// =====================================================================
// RNN scan v6 — dual-visibility data-as-flag.
// Placement fact: blockIdx%8 round-robins XCDs, so all 32 WGs of a
// batch LIKELY share one XCD; but correctness must not depend on it.
//  - Producer (wave0, lanes<32): pS gather -> ONE coalesced 128B line,
//    stored twice: sc0 (lands in own XCD L2: FAST, ~100ns if consumer
//    shares the XCD) then sc0 sc1 (write-through L3: always correct).
//  - Consumer (wave0 only; waves 1-7 parked at barrier — r7 proved
//    multi-wave spinning starves producers): poll fast (sc0); if
//    incomplete, poll slow (sc0 sc1) and MERGE per element (identical
//    values -> any interleaving correct). Same-XCD: detects via L2.
//    Split placement: detects via L3 (== round-6 behavior). No hangs.
//  - Compute core = round 6 (8 waves x 4 rows from LDS weights; same
//    FMA chains + XOR tree) -> scan BIT-IDENTICAL to r6/r7
//    (canary: absmax must stay exactly 0.0009765625).
// =====================================================================
__global__ __launch_bounds__(512, 1)
void rnn_scan(const float* __restrict__ Pre, float* __restrict__ Hout,
              const float* __restrict__ Whh, const float* __restrict__ bhh)
{
  __shared__ float wS[32][DIM];                 // 128 KB
  __shared__ __align__(16) float hbuf[DIM];     // 4 KB
  __shared__ float pS[8][8];
  const int b    = blockIdx.x & 7;
  const int p    = blockIdx.x >> 3;      // 0..31
  const int wv   = threadIdx.x >> 6;     // 0..7
  const int lane = threadIdx.x & 63;
  const int fl   = ((lane & 1) << 1) | ((lane >> 1) & 1);  // bitrev2

  const float* PreB = Pre  + (size_t)b * SEQ * DIM;
  float*       HB   = Hout + (size_t)b * SEQ * DIM;

  // stage this WG's 32 weight rows into LDS (coalesced float4)
  for (int i = threadIdx.x; i < 32 * (DIM / 4); i += 512) {
    const int row = i >> 8, c4 = i & 255;
    *(f32x4*)&wS[row][c4 * 4] =
        *(const f32x4*)&Whh[(size_t)(p * 32 + row) * DIM + c4 * 4];
  }
  __syncthreads();

  const bool w0lane = (wv == 0) && (lane < 32);
  const float biasv = w0lane ? bhh[p * 32 + lane] : 0.f;

  for (int t = 0; t < SEQ; ++t) {
    if (t > 0) {
      if (wv == 0) {
        const float* hp = HB + (size_t)(t - 1) * DIM;
        const float* q0 = hp +   0 + lane * 4;
        const float* q1 = hp + 256 + lane * 4;
        const float* q2 = hp + 512 + lane * 4;
        const float* q3 = hp + 768 + lane * 4;
        f32x4 m0, m1, m2, m3;
        while (true) {
          f32x4 f0, f1, f2, f3;
          asm volatile(                      // FAST: XCD-L2 view
            "global_load_dwordx4 %0, %4, off sc0\n\t"
            "global_load_dwordx4 %1, %5, off sc0\n\t"
            "global_load_dwordx4 %2, %6, off sc0\n\t"
            "global_load_dwordx4 %3, %7, off sc0\n\t"
            "s_waitcnt vmcnt(0)"
            : "=&v"(f0), "=&v"(f1), "=&v"(f2), "=&v"(f3)
            : "v"(q0), "v"(q1), "v"(q2), "v"(q3));
          bool gf = true;
#pragma unroll
          for (int j = 0; j < 4; ++j) {
            gf = gf && (__float_as_uint(f0[j]) != 0xFFFFFFFFu)
                    && (__float_as_uint(f1[j]) != 0xFFFFFFFFu)
                    && (__float_as_uint(f2[j]) != 0xFFFFFFFFu)
                    && (__float_as_uint(f3[j]) != 0xFFFFFFFFu);
          }
          if (__all(gf)) { m0 = f0; m1 = f1; m2 = f2; m3 = f3; break; }

          f32x4 s0, s1, s2, s3;
          asm volatile(                      // SLOW: L3 view (always correct)
            "global_load_dwordx4 %0, %4, off sc0 sc1\n\t"
            "global_load_dwordx4 %1, %5, off sc0 sc1\n\t"
            "global_load_dwordx4 %2, %6, off sc0 sc1\n\t"
            "global_load_dwordx4 %3, %7, off sc0 sc1\n\t"
            "s_waitcnt vmcnt(0)"
            : "=&v"(s0), "=&v"(s1), "=&v"(s2), "=&v"(s3)
            : "v"(q0), "v"(q1), "v"(q2), "v"(q3));
          bool gm = true;
#pragma unroll
          for (int j = 0; j < 4; ++j) {
            m0[j] = (__float_as_uint(f0[j]) != 0xFFFFFFFFu) ? f0[j] : s0[j];
            m1[j] = (__float_as_uint(f1[j]) != 0xFFFFFFFFu) ? f1[j] : s1[j];
            m2[j] = (__float_as_uint(f2[j]) != 0xFFFFFFFFu) ? f2[j] : s2[j];
            m3[j] = (__float_as_uint(f3[j]) != 0xFFFFFFFFu) ? f3[j] : s3[j];
            gm = gm && (__float_as_uint(m0[j]) != 0xFFFFFFFFu)
                    && (__float_as_uint(m1[j]) != 0xFFFFFFFFu)
                    && (__float_as_uint(m2[j]) != 0xFFFFFFFFu)
                    && (__float_as_uint(m3[j]) != 0xFFFFFFFFu);
          }
          if (__all(gm)) break;
        }
        *(f32x4*)&hbuf[  0 + lane * 4] = m0;
        *(f32x4*)&hbuf[256 + lane * 4] = m1;
        *(f32x4*)&hbuf[512 + lane * 4] = m2;
        *(f32x4*)&hbuf[768 + lane * 4] = m3;
      }
      __syncthreads();   // A: hbuf ready
      const f32x4 h0 = *(const f32x4*)&hbuf[  0 + lane * 4];
      const f32x4 h1 = *(const f32x4*)&hbuf[256 + lane * 4];
      const f32x4 h2 = *(const f32x4*)&hbuf[512 + lane * 4];
      const f32x4 h3 = *(const f32x4*)&hbuf[768 + lane * 4];
      float acc[4];
#pragma unroll
      for (int r = 0; r < 4; ++r) {
        const f32x4 w0 = *(const f32x4*)&wS[wv * 4 + r][  0 + lane * 4];
        const f32x4 w1 = *(const f32x4*)&wS[wv * 4 + r][256 + lane * 4];
        const f32x4 w2 = *(const f32x4*)&wS[wv * 4 + r][512 + lane * 4];
        const f32x4 w3 = *(const f32x4*)&wS[wv * 4 + r][768 + lane * 4];
        float a = 0.f;
        a = fmaf(w0.x, h0.x, fmaf(w0.y, h0.y, fmaf(w0.z, h0.z, fmaf(w0.w, h0.w, a))));
        a = fmaf(w1.x, h1.x, fmaf(w1.y, h1.y, fmaf(w1.z, h1.z, fmaf(w1.w, h1.w, a))));
        a = fmaf(w2.x, h2.x, fmaf(w2.y, h2.y, fmaf(w2.z, h2.z, fmaf(w2.w, h2.w, a))));
        a = fmaf(w3.x, h3.x, fmaf(w3.y, h3.y, fmaf(w3.z, h3.z, fmaf(w3.w, h3.w, a))));
        acc[r] = a;
      }
      // fold 4 accs over masks 1,2 (same XOR tree as r6 -> bit-identical)
#pragma unroll
      for (int m = 0; m < 2; ++m) {
        const int mask = 1 << m;
        const int nv   = 2 >> m;
        const bool up  = (lane & mask) != 0;
#pragma unroll
        for (int r = 0; r < nv; ++r) {
          const float lo = up ? acc[r + nv] : acc[r];
          const float hi = up ? acc[r] : acc[r + nv];
          acc[r] = lo + __shfl_xor(hi, mask);
        }
      }
#pragma unroll
      for (int off = 4; off < 64; off <<= 1) acc[0] += __shfl_xor(acc[0], off);

      if (lane < 4) pS[wv][fl] = acc[0];
      __syncthreads();   // B: pS ready
    }

    if (w0lane) {
      const float pre = PreB[(size_t)t * DIM + p * 32 + lane];
      float s = (t > 0) ? (pre + pS[lane >> 2][lane & 3] + biasv)
                        : (pre + biasv);
      const float v = fast_tanh(s);
      float* dst = HB + (size_t)t * DIM + p * 32 + lane;
      asm volatile(
        "global_store_dword %0, %1, off sc0\n\t"        // fast: own-XCD L2
        "global_store_dword %0, %1, off sc0 sc1"        // slow: through to L3
        :: "v"(dst), "v"(v));
    }
  }
}

// =====================================================================
// Masked softmax, in place, one row per block
// =====================================================================
__global__ __launch_bounds__(256)
void softmax_mask(float* __restrict__ S, const unsigned char* __restrict__ mask)
{
  const size_t row = (size_t)blockIdx.y * gridDim.x + blockIdx.x;
  float* p = S + row * SEQ;
  const unsigned char* mrow = mask + row * SEQ;
  __shared__ float buf[SEQ];
  __shared__ float red[4];
  const int tid = threadIdx.x, lane = tid & 63, wv = tid >> 6;

  float mx = -1e30f;
  for (int i = tid; i < SEQ; i += 256) {
    const float v = mrow[i] ? -1e9f : p[i];
    buf[i] = v;
    mx = fmaxf(mx, v);
  }
#pragma unroll
  for (int off = 1; off < 64; off <<= 1) mx = fmaxf(mx, __shfl_xor(mx, off));
  if (lane == 0) red[wv] = mx;
  __syncthreads();
  mx = fmaxf(fmaxf(red[0], red[1]), fmaxf(red[2], red[3]));

  float s = 0.f;
  for (int i = tid; i < SEQ; i += 256) {
    const float e = __expf(buf[i] - mx);
    buf[i] = e;
    s += e;
  }
#pragma unroll
  for (int off = 1; off < 64; off <<= 1) s += __shfl_xor(s, off);
  __syncthreads();
  if (lane == 0) red[wv] = s;
  __syncthreads();
  s = red[0] + red[1] + red[2] + red[3];
  const float inv = 1.f / s;
  for (int i = tid; i < SEQ; i += 256) p[i] = buf[i] * inv;
}

// =====================================================================
extern "C" void kernel_launch(void* const* d_in, const int* in_sizes, int n_in,
                              void* d_out, int out_size, void* d_ws, size_t ws_size,
                              hipStream_t stream)
{
  (void)in_sizes; (void)n_in; (void)out_size;
  const unsigned char* mask = (const unsigned char*)d_in[0];
  const float* reps = (const float*)d_in[1];
  const float* Wih  = (const float*)d_in[2];
  const float* Whh  = (const float*)d_in[3];
  const float* bih  = (const float*)d_in[4];
  const float* bhh  = (const float*)d_in[5];
  const float* Wq   = (const float*)d_in[6];
  const float* bq   = (const float*)d_in[7];
  const float* Wk   = (const float*)d_in[8];
  const float* bk   = (const float*)d_in[9];
  const float* Wv   = (const float*)d_in[10];
  const float* bv   = (const float*)d_in[11];
  const float* Wo   = (const float*)d_in[12];
  const float* bo   = (const float*)d_in[13];
  float* out = (float*)d_out;

  char* ws = (char*)d_ws;
  float* Hb = (float*)(ws);
  float* Qb = (float*)(ws + ((size_t)64  << 20));
  float* Kb = (float*)(ws + ((size_t)128 << 20));
  float* Vb = (float*)(ws + ((size_t)192 << 20));
  float* Sb = (float*)(ws + ((size_t)256 << 20));
  const size_t needFull = ((size_t)256 << 20) + (size_t)BATCH * SEQ * SEQ * 4;
  const bool fullS = ws_size >= needFull;
  const size_t hBytes = (size_t)BATCH * SEQ * DIM * 4;

  const int M1 = BATCH * SEQ;
  const float scale = 0.03125f;
  const dim3 blk(256);
  const long long sSD = (long long)SEQ * DIM;
  const long long sSS = (long long)SEQ * SEQ;

  const float* X = reps;
  for (int l = 0; l < NLAYER; ++l) {
    const size_t wof = (size_t)l * DIM * DIM;
    const size_t bof = (size_t)l * DIM;
    float* Y = (l == NLAYER - 1) ? out : Qb;

    hipMemsetAsync(Hb, 0xFF, hBytes, stream);
    gemm_bf16x3<1><<<dim3(M1/128, DIM/128, 1), blk, 0, stream>>>(
        X, Wih + wof, bih + bof, Kb, M1, DIM, DIM, 1.f, 0, 0, 0);
    rnn_scan<<<dim3(256), dim3(512), 0, stream>>>(Kb, Hb, Whh + wof, bhh + bof);

    gemm_bf16x3<1><<<dim3(M1/128, DIM/128, 1), blk, 0, stream>>>(
        Hb, Wq + wof, bq + bof, Qb, M1, DIM, DIM, 1.f, 0, 0, 0);
    gemm_bf16x3<1><<<dim3(M1/128, DIM/128, 1), blk, 0, stream>>>(
        Hb, Wk + wof, bk + bof, Kb, M1, DIM, DIM, 1.f, 0, 0, 0);
    gemm_bf16x3<1><<<dim3(M1/128, DIM/128, 1), blk, 0, stream>>>(
        Hb, Wv + wof, bv + bof, Vb, M1, DIM, DIM, 1.f, 0, 0, 0);

    if (fullS) {
      gemm_bf16x3<1><<<dim3(SEQ/128, SEQ/128, BATCH), blk, 0, stream>>>(
          Qb, Kb, nullptr, Sb, SEQ, SEQ, DIM, scale, sSD, sSD, sSS);
      softmax_mask<<<dim3(SEQ, BATCH), blk, 0, stream>>>(Sb, mask);
      gemm_bf16x3<0><<<dim3(SEQ/128, DIM/128, BATCH), blk, 0, stream>>>(
          Sb, Vb, nullptr, Hb, SEQ, DIM, SEQ, 1.f, sSS, sSD, sSD);
    } else {
      for (int bb = 0; bb < BATCH; ++bb) {
        gemm_bf16x3<1><<<dim3(SEQ/128, SEQ/128, 1), blk, 0, stream>>>(
            Qb + (size_t)bb * sSD, Kb + (size_t)bb * sSD, nullptr, Sb,
            SEQ, SEQ, DIM, scale, 0, 0, 0);
        softmax_mask<<<dim3(SEQ, 1), blk, 0, stream>>>(Sb, mask + (size_t)bb * sSS);
        gemm_bf16x3<0><<<dim3(SEQ/128, DIM/128, 1), blk, 0, stream>>>(
            Sb, Vb + (size_t)bb * sSD, nullptr, Hb + (size_t)bb * sSD,
            SEQ, DIM, SEQ, 1.f, 0, 0, 0);
      }
    }
    gemm_bf16x3<1><<<dim3(M1/128, DIM/128, 1), blk, 0, stream>>>(
        Hb, Wo + wof, bo + bof, Y, M1, DIM, DIM, 1.f, 0, 0, 0);
    X = Y;
  }
}